// Round 1
// baseline (1347.969 us; speedup 1.0000x reference)
//
#include <hip/hip_runtime.h>
#include <hip/hip_bf16.h>
#include <cstdint>

#define F_IN 256
#define C 128

static inline size_t align256(size_t x) { return (x + 255) & ~(size_t)255; }

// ---------------- graph preprocessing ----------------

__global__ void deg_count_kernel(const int* __restrict__ dst, int* __restrict__ degc, int E) {
    int i = blockIdx.x * blockDim.x + threadIdx.x;
    if (i < E) atomicAdd(&degc[dst[i]], 1);
}

__global__ void dinv_kernel(const int* __restrict__ degc, float* __restrict__ dinv, int n) {
    int i = blockIdx.x * blockDim.x + threadIdx.x;
    if (i < n) dinv[i] = rsqrtf((float)degc[i] + 1.0f);
}

// Single-block exclusive scan of (degc[i]+1) -> offs[0..n], offs[n] = total.
__global__ __launch_bounds__(1024) void scan_kernel(const int* __restrict__ degc,
                                                    int* __restrict__ offs, int n) {
    __shared__ int sums[1024];
    int tid = threadIdx.x;
    int per = (n + 1023) >> 10;
    int s = tid * per, e = min(s + per, n);
    int loc = 0;
    for (int i = s; i < e; ++i) loc += degc[i] + 1;
    sums[tid] = loc;
    __syncthreads();
    // Hillis-Steele inclusive scan
    for (int d = 1; d < 1024; d <<= 1) {
        int v = (tid >= d) ? sums[tid - d] : 0;
        __syncthreads();
        sums[tid] += v;
        __syncthreads();
    }
    int run = (tid == 0) ? 0 : sums[tid - 1];
    for (int i = s; i < e; ++i) { offs[i] = run; run += degc[i] + 1; }
    if (tid == 1023) offs[n] = run;
}

// Self-loop entry first in each node's list: coef = dinv^2
__global__ void self_fill_kernel(const int* __restrict__ offs, const float* __restrict__ dinv,
                                 int* __restrict__ csr_src, float* __restrict__ csr_coef, int n) {
    int i = blockIdx.x * blockDim.x + threadIdx.x;
    if (i < n) {
        int o = offs[i];
        csr_src[o] = i;
        float d = dinv[i];
        csr_coef[o] = d * d;
    }
}

__global__ void edge_fill_kernel(const int* __restrict__ src, const int* __restrict__ dst,
                                 const int* __restrict__ offs, const float* __restrict__ dinv,
                                 int* __restrict__ cursor, int* __restrict__ csr_src,
                                 float* __restrict__ csr_coef, int E) {
    int e = blockIdx.x * blockDim.x + threadIdx.x;
    if (e < E) {
        int d = dst[e], s = src[e];
        int p = atomicAdd(&cursor[d], 1);
        int idx = offs[d] + 1 + p;
        csr_src[idx] = s;
        csr_coef[idx] = dinv[s] * dinv[d];
    }
}

// ---------------- fp32 GEMM: H[M,128] = X[M,K] @ W[K,128] ----------------
// tile 64 rows x 128 cols, K-chunks of 16; thread micro-tile 4x8.
__global__ __launch_bounds__(256) void gemm_kernel(const float* __restrict__ X,
                                                   const float* __restrict__ W,
                                                   float* __restrict__ H, int M, int K) {
    __shared__ float Ast[16][64];    // [kk][row]  (transposed A tile)
    __shared__ float Bs[16][C];      // [kk][col]
    const int tid = threadIdx.x;
    const int cg = tid & 15;         // cols cg*8 .. cg*8+7
    const int rg = tid >> 4;         // rows rg*4 .. rg*4+3
    const int row0 = blockIdx.x * 64;

    const int lrow = tid >> 2;              // 0..63
    const int lkq  = (tid & 3) * 4;         // 0,4,8,12
    const int bk = tid >> 5;                // 0..7
    const int bc = (tid & 31) * 4;          // 0..124

    float acc[4][8] = {};

    for (int k0 = 0; k0 < K; k0 += 16) {
        float4 av = make_float4(0.f, 0.f, 0.f, 0.f);
        int gr = row0 + lrow;
        if (gr < M) av = *(const float4*)(X + (size_t)gr * K + k0 + lkq);
        float4 bv0 = *(const float4*)(W + (size_t)(k0 + bk) * C + bc);
        float4 bv1 = *(const float4*)(W + (size_t)(k0 + bk + 8) * C + bc);
        __syncthreads();
        Ast[lkq + 0][lrow] = av.x;
        Ast[lkq + 1][lrow] = av.y;
        Ast[lkq + 2][lrow] = av.z;
        Ast[lkq + 3][lrow] = av.w;
        *(float4*)&Bs[bk][bc] = bv0;
        *(float4*)&Bs[bk + 8][bc] = bv1;
        __syncthreads();
#pragma unroll
        for (int kk = 0; kk < 16; ++kk) {
            float4 a  = *(const float4*)&Ast[kk][rg * 4];
            float4 b0 = *(const float4*)&Bs[kk][cg * 8];
            float4 b1 = *(const float4*)&Bs[kk][cg * 8 + 4];
            float as[4] = {a.x, a.y, a.z, a.w};
            float bs[8] = {b0.x, b0.y, b0.z, b0.w, b1.x, b1.y, b1.z, b1.w};
#pragma unroll
            for (int i = 0; i < 4; ++i)
#pragma unroll
                for (int j = 0; j < 8; ++j) acc[i][j] += as[i] * bs[j];
        }
    }
#pragma unroll
    for (int i = 0; i < 4; ++i) {
        int r = row0 + rg * 4 + i;
        if (r < M) {
            float4 o0 = make_float4(acc[i][0], acc[i][1], acc[i][2], acc[i][3]);
            float4 o1 = make_float4(acc[i][4], acc[i][5], acc[i][6], acc[i][7]);
            *(float4*)(H + (size_t)r * C + cg * 8) = o0;
            *(float4*)(H + (size_t)r * C + cg * 8 + 4) = o1;
        }
    }
}

// ---------------- aggregation: out[i] = relu(sum_k coef*H[src] + bias) ----------------
// one block (128 threads = 128 channels) per node; self-loop is in the CSR.
__global__ __launch_bounds__(128) void agg_kernel(const float* __restrict__ H,
                                                  const int* __restrict__ csr_src,
                                                  const float* __restrict__ csr_coef,
                                                  const int* __restrict__ offs,
                                                  const float* __restrict__ bias,
                                                  float* __restrict__ Out) {
    __shared__ int s_idx[128];
    __shared__ float s_w[128];
    const int node = blockIdx.x;
    const int tid = threadIdx.x;
    const int beg = offs[node], end = offs[node + 1];
    float acc = 0.f;
    for (int base = beg; base < end; base += 128) {
        int cnt = min(128, end - base);
        if (tid < cnt) {
            s_idx[tid] = csr_src[base + tid];
            s_w[tid] = csr_coef[base + tid];
        }
        __syncthreads();
#pragma unroll 4
        for (int j = 0; j < cnt; ++j)
            acc += H[(size_t)s_idx[j] * C + tid] * s_w[j];
        __syncthreads();
    }
    Out[(size_t)node * C + tid] = fmaxf(acc + bias[tid], 0.f);
}

// ---------------- masked pool accumulate: pooled[b,c] += sum_n mask*S ----------------
__global__ __launch_bounds__(128) void pool_kernel(const float* __restrict__ S,
                                                   const int* __restrict__ mask,
                                                   float* __restrict__ pooled, int N) {
    const int b = blockIdx.y;
    const int n0 = blockIdx.x * 512;
    const int c = threadIdx.x;
    const int lim = min(n0 + 512, N);
    float acc = 0.f;
    for (int n = n0; n < lim; ++n) {
        if (mask[b * N + n]) acc += S[((size_t)b * N + n) * C + c];
    }
    atomicAdd(&pooled[b * C + c], acc);
}

// ---------------- MLP head: [4,128]->256->64->16->1 ----------------
__global__ __launch_bounds__(256) void mlp_kernel(const float* __restrict__ pooled,
        const float* __restrict__ lw1, const float* __restrict__ lb1,
        const float* __restrict__ lw2, const float* __restrict__ lb2,
        const float* __restrict__ lw3, const float* __restrict__ lb3,
        const float* __restrict__ lw4, const float* __restrict__ lb4,
        float* __restrict__ out) {
    __shared__ float p[4 * 128];
    __shared__ float z1[4 * 256];
    __shared__ float z2[4 * 64];
    __shared__ float z3[4 * 16];
    const int tid = threadIdx.x;
    for (int i = tid; i < 4 * 128; i += 256) p[i] = pooled[i];
    __syncthreads();
    for (int o = tid; o < 4 * 256; o += 256) {
        int b = o >> 8, j = o & 255;
        float s = lb1[j];
        for (int k = 0; k < 128; ++k) s += p[b * 128 + k] * lw1[k * 256 + j];
        z1[o] = fmaxf(s, 0.f);
    }
    __syncthreads();
    for (int o = tid; o < 4 * 64; o += 256) {
        int b = o >> 6, j = o & 63;
        float s = lb2[j];
        for (int k = 0; k < 256; ++k) s += z1[b * 256 + k] * lw2[k * 64 + j];
        z2[o] = fmaxf(s, 0.f);
    }
    __syncthreads();
    if (tid < 64) {
        int b = tid >> 4, j = tid & 15;
        float s = lb3[j];
        for (int k = 0; k < 64; ++k) s += z2[b * 64 + k] * lw3[k * 16 + j];
        z3[tid] = fmaxf(s, 0.f);
    }
    __syncthreads();
    if (tid < 4) {
        float s = lb4[0];
        for (int k = 0; k < 16; ++k) s += z3[tid * 16 + k] * lw4[k];
        out[tid] = s;
    }
}

// ---------------- launcher ----------------

extern "C" void kernel_launch(void* const* d_in, const int* in_sizes, int n_in,
                              void* d_out, int out_size, void* d_ws, size_t ws_size,
                              hipStream_t stream) {
    const float* x    = (const float*)d_in[0];
    const int*   ei   = (const int*)d_in[1];
    const int*   pmask = (const int*)d_in[2];
    const float* W1 = (const float*)d_in[3];  const float* b1 = (const float*)d_in[4];
    const float* W2 = (const float*)d_in[5];  const float* b2 = (const float*)d_in[6];
    const float* W3 = (const float*)d_in[7];  const float* b3 = (const float*)d_in[8];
    const float* lw1 = (const float*)d_in[9];  const float* lb1 = (const float*)d_in[10];
    const float* lw2 = (const float*)d_in[11]; const float* lb2 = (const float*)d_in[12];
    const float* lw3 = (const float*)d_in[13]; const float* lb3 = (const float*)d_in[14];
    const float* lw4 = (const float*)d_in[15]; const float* lb4 = (const float*)d_in[16];
    float* out = (float*)d_out;

    const int E = in_sizes[1] / 2;
    const int NODES = in_sizes[0] / F_IN;
    const int NB = 4;
    const int NPER = NODES / NB;   // 17000
    const int* esrc = ei;
    const int* edst = ei + E;

    char* w = (char*)d_ws;
    size_t off = 0;
    auto alloc = [&](size_t bytes) -> void* {
        void* p = w + off;
        off = align256(off + bytes);
        return p;
    };
    int*   degc     = (int*)  alloc((size_t)NODES * 4);
    float* dinv     = (float*)alloc((size_t)NODES * 4);
    int*   offs     = (int*)  alloc((size_t)(NODES + 1) * 4);
    int*   cursor   = (int*)  alloc((size_t)NODES * 4);
    int*   csr_src  = (int*)  alloc((size_t)(E + NODES) * 4);
    float* csr_coef = (float*)alloc((size_t)(E + NODES) * 4);
    float* Hb  = (float*)alloc((size_t)NODES * C * 4);
    float* Bu1 = (float*)alloc((size_t)NODES * C * 4);
    float* Bu2 = (float*)alloc((size_t)NODES * C * 4);
    float* pooled = (float*)alloc((size_t)4 * C * 4);
    (void)ws_size; (void)n_in; (void)out_size;

    hipMemsetAsync(degc,   0, (size_t)NODES * 4, stream);
    hipMemsetAsync(cursor, 0, (size_t)NODES * 4, stream);
    hipMemsetAsync(pooled, 0, (size_t)4 * C * 4, stream);

    deg_count_kernel<<<(E + 255) / 256, 256, 0, stream>>>(edst, degc, E);
    dinv_kernel<<<(NODES + 255) / 256, 256, 0, stream>>>(degc, dinv, NODES);
    scan_kernel<<<1, 1024, 0, stream>>>(degc, offs, NODES);
    self_fill_kernel<<<(NODES + 255) / 256, 256, 0, stream>>>(offs, dinv, csr_src, csr_coef, NODES);
    edge_fill_kernel<<<(E + 255) / 256, 256, 0, stream>>>(esrc, edst, offs, dinv, cursor,
                                                          csr_src, csr_coef, E);

    dim3 pgrid((NPER + 511) / 512, NB);

    // layer 1
    gemm_kernel<<<(NODES + 63) / 64, 256, 0, stream>>>(x, W1, Hb, NODES, F_IN);
    agg_kernel<<<NODES, 128, 0, stream>>>(Hb, csr_src, csr_coef, offs, b1, Bu1);
    pool_kernel<<<pgrid, 128, 0, stream>>>(Bu1, pmask, pooled, NPER);
    // layer 2
    gemm_kernel<<<(NODES + 63) / 64, 256, 0, stream>>>(Bu1, W2, Hb, NODES, C);
    agg_kernel<<<NODES, 128, 0, stream>>>(Hb, csr_src, csr_coef, offs, b2, Bu2);
    pool_kernel<<<pgrid, 128, 0, stream>>>(Bu2, pmask, pooled, NPER);
    // layer 3
    gemm_kernel<<<(NODES + 63) / 64, 256, 0, stream>>>(Bu2, W3, Hb, NODES, C);
    agg_kernel<<<NODES, 128, 0, stream>>>(Hb, csr_src, csr_coef, offs, b3, Bu1);
    pool_kernel<<<pgrid, 128, 0, stream>>>(Bu1, pmask, pooled, NPER);

    mlp_kernel<<<1, 256, 0, stream>>>(pooled, lw1, lb1, lw2, lb2, lw3, lb3, lw4, lb4, out);
}

// Round 2
// 896.904 us; speedup vs baseline: 1.5029x; 1.5029x over previous
//
#include <hip/hip_runtime.h>
#include <hip/hip_bf16.h>
#include <cstdint>

#define F_IN 256
#define C 128

static inline size_t align256(size_t x) { return (x + 255) & ~(size_t)255; }

// ---------------- graph preprocessing ----------------

__global__ void deg_count_kernel(const int* __restrict__ dst, int* __restrict__ degc, int E) {
    int i = blockIdx.x * blockDim.x + threadIdx.x;
    if (i < E) atomicAdd(&degc[dst[i]], 1);
}

__global__ void dinv_kernel(const int* __restrict__ degc, float* __restrict__ dinv, int n) {
    int i = blockIdx.x * blockDim.x + threadIdx.x;
    if (i < n) dinv[i] = rsqrtf((float)degc[i] + 1.0f);
}

// Single-block exclusive scan of (degc[i]+1) -> offs[0..n], offs[n] = total.
__global__ __launch_bounds__(1024) void scan_kernel(const int* __restrict__ degc,
                                                    int* __restrict__ offs, int n) {
    __shared__ int sums[1024];
    int tid = threadIdx.x;
    int per = (n + 1023) >> 10;
    int s = tid * per, e = min(s + per, n);
    int loc = 0;
    for (int i = s; i < e; ++i) loc += degc[i] + 1;
    sums[tid] = loc;
    __syncthreads();
    for (int d = 1; d < 1024; d <<= 1) {
        int v = (tid >= d) ? sums[tid - d] : 0;
        __syncthreads();
        sums[tid] += v;
        __syncthreads();
    }
    int run = (tid == 0) ? 0 : sums[tid - 1];
    for (int i = s; i < e; ++i) { offs[i] = run; run += degc[i] + 1; }
    if (tid == 1023) offs[n] = run;
}

// CSR entry: 8-byte packed {src, coef-bits} -> single scattered store per edge.
__global__ void self_fill_kernel(const int* __restrict__ offs, const float* __restrict__ dinv,
                                 int2* __restrict__ csr, int n) {
    int i = blockIdx.x * blockDim.x + threadIdx.x;
    if (i < n) {
        float d = dinv[i];
        int2 ent;
        ent.x = i;
        ent.y = __float_as_int(d * d);
        csr[offs[i]] = ent;
    }
}

__global__ void edge_fill_kernel(const int* __restrict__ src, const int* __restrict__ dst,
                                 const int* __restrict__ offs, const float* __restrict__ dinv,
                                 int* __restrict__ cursor, int2* __restrict__ csr, int E) {
    int e = blockIdx.x * blockDim.x + threadIdx.x;
    if (e < E) {
        int d = dst[e], s = src[e];
        int p = atomicAdd(&cursor[d], 1);
        int2 ent;
        ent.x = s;
        ent.y = __float_as_int(dinv[s] * dinv[d]);
        csr[offs[d] + 1 + p] = ent;
    }
}

// ---------------- fp32 GEMM: H[M,128] = X[M,K] @ W[K,128], bf16 output ----------------
// tile 64 rows x 128 cols, K-chunks of 16; thread micro-tile 4x8.

static __device__ inline unsigned pack_bf16(float a, float b) {
    __hip_bfloat162 h = __float22bfloat162_rn(make_float2(a, b));
    return *(unsigned*)&h;
}

__global__ __launch_bounds__(256) void gemm_kernel(const float* __restrict__ X,
                                                   const float* __restrict__ W,
                                                   __hip_bfloat16* __restrict__ H,
                                                   int M, int K) {
    __shared__ float Ast[16][64];    // [kk][row]  (transposed A tile)
    __shared__ float Bs[16][C];      // [kk][col]
    const int tid = threadIdx.x;
    const int cg = tid & 15;         // cols cg*8 .. cg*8+7
    const int rg = tid >> 4;         // rows rg*4 .. rg*4+3
    const int row0 = blockIdx.x * 64;

    const int lrow = tid >> 2;              // 0..63
    const int lkq  = (tid & 3) * 4;         // 0,4,8,12
    const int bk = tid >> 5;                // 0..7
    const int bc = (tid & 31) * 4;          // 0..124

    float acc[4][8] = {};

    for (int k0 = 0; k0 < K; k0 += 16) {
        float4 av = make_float4(0.f, 0.f, 0.f, 0.f);
        int gr = row0 + lrow;
        if (gr < M) av = *(const float4*)(X + (size_t)gr * K + k0 + lkq);
        float4 bv0 = *(const float4*)(W + (size_t)(k0 + bk) * C + bc);
        float4 bv1 = *(const float4*)(W + (size_t)(k0 + bk + 8) * C + bc);
        __syncthreads();
        Ast[lkq + 0][lrow] = av.x;
        Ast[lkq + 1][lrow] = av.y;
        Ast[lkq + 2][lrow] = av.z;
        Ast[lkq + 3][lrow] = av.w;
        *(float4*)&Bs[bk][bc] = bv0;
        *(float4*)&Bs[bk + 8][bc] = bv1;
        __syncthreads();
#pragma unroll
        for (int kk = 0; kk < 16; ++kk) {
            float4 a  = *(const float4*)&Ast[kk][rg * 4];
            float4 b0 = *(const float4*)&Bs[kk][cg * 8];
            float4 b1 = *(const float4*)&Bs[kk][cg * 8 + 4];
            float as[4] = {a.x, a.y, a.z, a.w};
            float bs[8] = {b0.x, b0.y, b0.z, b0.w, b1.x, b1.y, b1.z, b1.w};
#pragma unroll
            for (int i = 0; i < 4; ++i)
#pragma unroll
                for (int j = 0; j < 8; ++j) acc[i][j] += as[i] * bs[j];
        }
    }
#pragma unroll
    for (int i = 0; i < 4; ++i) {
        int r = row0 + rg * 4 + i;
        if (r < M) {
            uint4 ov;
            ov.x = pack_bf16(acc[i][0], acc[i][1]);
            ov.y = pack_bf16(acc[i][2], acc[i][3]);
            ov.z = pack_bf16(acc[i][4], acc[i][5]);
            ov.w = pack_bf16(acc[i][6], acc[i][7]);
            *(uint4*)(H + (size_t)r * C + cg * 8) = ov;
        }
    }
}

// ---------------- aggregation: out[i] = relu(sum_k coef*H[src] + bias) ----------------
// one block (64 threads, 2 channels each) per node; self-loop is in the CSR.
__global__ __launch_bounds__(64) void agg_kernel(const __hip_bfloat16* __restrict__ H,
                                                 const int2* __restrict__ csr,
                                                 const int* __restrict__ offs,
                                                 const float* __restrict__ bias,
                                                 float* __restrict__ Out) {
    __shared__ int2 s_e[64];
    const int node = blockIdx.x;
    const int tid = threadIdx.x;
    const int c0 = tid * 2;
    const int beg = offs[node], end = offs[node + 1];
    float accx = 0.f, accy = 0.f;
    for (int base = beg; base < end; base += 64) {
        int cnt = min(64, end - base);
        if (tid < cnt) s_e[tid] = csr[base + tid];
        __syncthreads();
#pragma unroll 4
        for (int j = 0; j < cnt; ++j) {
            int2 e = s_e[j];
            float w = __int_as_float(e.y);
            __hip_bfloat162 hv = *(const __hip_bfloat162*)(H + (size_t)e.x * C + c0);
            float2 f = __bfloat1622float2(hv);
            accx += f.x * w;
            accy += f.y * w;
        }
        __syncthreads();
    }
    float2 o;
    o.x = fmaxf(accx + bias[c0], 0.f);
    o.y = fmaxf(accy + bias[c0 + 1], 0.f);
    *(float2*)(Out + (size_t)node * C + c0) = o;
}

// ---------------- masked pool accumulate: pooled[b,c] += sum_n mask*S ----------------
__global__ __launch_bounds__(128) void pool_kernel(const float* __restrict__ S,
                                                   const int* __restrict__ mask,
                                                   float* __restrict__ pooled, int N) {
    const int b = blockIdx.y;
    const int n0 = blockIdx.x * 128;
    const int c = threadIdx.x;
    const int lim = min(n0 + 128, N);
    float acc = 0.f;
    for (int n = n0; n < lim; ++n) {
        if (mask[b * N + n]) acc += S[((size_t)b * N + n) * C + c];
    }
    atomicAdd(&pooled[b * C + c], acc);
}

// ---------------- MLP head: [4,128]->256->64->16->1 ----------------
__global__ __launch_bounds__(256) void mlp_kernel(const float* __restrict__ pooled,
        const float* __restrict__ lw1, const float* __restrict__ lb1,
        const float* __restrict__ lw2, const float* __restrict__ lb2,
        const float* __restrict__ lw3, const float* __restrict__ lb3,
        const float* __restrict__ lw4, const float* __restrict__ lb4,
        float* __restrict__ out) {
    __shared__ float p[4 * 128];
    __shared__ float z1[4 * 256];
    __shared__ float z2[4 * 64];
    __shared__ float z3[4 * 16];
    const int tid = threadIdx.x;
    for (int i = tid; i < 4 * 128; i += 256) p[i] = pooled[i];
    __syncthreads();
    for (int o = tid; o < 4 * 256; o += 256) {
        int b = o >> 8, j = o & 255;
        float s = lb1[j];
        for (int k = 0; k < 128; ++k) s += p[b * 128 + k] * lw1[k * 256 + j];
        z1[o] = fmaxf(s, 0.f);
    }
    __syncthreads();
    for (int o = tid; o < 4 * 64; o += 256) {
        int b = o >> 6, j = o & 63;
        float s = lb2[j];
        for (int k = 0; k < 256; ++k) s += z1[b * 256 + k] * lw2[k * 64 + j];
        z2[o] = fmaxf(s, 0.f);
    }
    __syncthreads();
    if (tid < 64) {
        int b = tid >> 4, j = tid & 15;
        float s = lb3[j];
        for (int k = 0; k < 64; ++k) s += z2[b * 64 + k] * lw3[k * 16 + j];
        z3[tid] = fmaxf(s, 0.f);
    }
    __syncthreads();
    if (tid < 4) {
        float s = lb4[0];
        for (int k = 0; k < 16; ++k) s += z3[tid * 16 + k] * lw4[k];
        out[tid] = s;
    }
}

// ---------------- launcher ----------------

extern "C" void kernel_launch(void* const* d_in, const int* in_sizes, int n_in,
                              void* d_out, int out_size, void* d_ws, size_t ws_size,
                              hipStream_t stream) {
    const float* x    = (const float*)d_in[0];
    const int*   ei   = (const int*)d_in[1];
    const int*   pmask = (const int*)d_in[2];
    const float* W1 = (const float*)d_in[3];  const float* b1 = (const float*)d_in[4];
    const float* W2 = (const float*)d_in[5];  const float* b2 = (const float*)d_in[6];
    const float* W3 = (const float*)d_in[7];  const float* b3 = (const float*)d_in[8];
    const float* lw1 = (const float*)d_in[9];  const float* lb1 = (const float*)d_in[10];
    const float* lw2 = (const float*)d_in[11]; const float* lb2 = (const float*)d_in[12];
    const float* lw3 = (const float*)d_in[13]; const float* lb3 = (const float*)d_in[14];
    const float* lw4 = (const float*)d_in[15]; const float* lb4 = (const float*)d_in[16];
    float* out = (float*)d_out;

    const int E = in_sizes[1] / 2;
    const int NODES = in_sizes[0] / F_IN;
    const int NB = 4;
    const int NPER = NODES / NB;   // 17000
    const int* esrc = ei;
    const int* edst = ei + E;

    char* w = (char*)d_ws;
    size_t off = 0;
    auto alloc = [&](size_t bytes) -> void* {
        void* p = w + off;
        off = align256(off + bytes);
        return p;
    };
    int*   degc     = (int*)  alloc((size_t)NODES * 4);
    float* dinv     = (float*)alloc((size_t)NODES * 4);
    int*   offs     = (int*)  alloc((size_t)(NODES + 1) * 4);
    int*   cursor   = (int*)  alloc((size_t)NODES * 4);
    int2*  csr      = (int2*) alloc((size_t)(E + NODES) * 8);
    __hip_bfloat16* Hb = (__hip_bfloat16*)alloc((size_t)NODES * C * 2);
    float* Bu1 = (float*)alloc((size_t)NODES * C * 4);
    float* Bu2 = (float*)alloc((size_t)NODES * C * 4);
    float* pooled = (float*)alloc((size_t)4 * C * 4);
    (void)ws_size; (void)n_in; (void)out_size;

    hipMemsetAsync(degc,   0, (size_t)NODES * 4, stream);
    hipMemsetAsync(cursor, 0, (size_t)NODES * 4, stream);
    hipMemsetAsync(pooled, 0, (size_t)4 * C * 4, stream);

    deg_count_kernel<<<(E + 255) / 256, 256, 0, stream>>>(edst, degc, E);
    dinv_kernel<<<(NODES + 255) / 256, 256, 0, stream>>>(degc, dinv, NODES);
    scan_kernel<<<1, 1024, 0, stream>>>(degc, offs, NODES);
    self_fill_kernel<<<(NODES + 255) / 256, 256, 0, stream>>>(offs, dinv, csr, NODES);
    edge_fill_kernel<<<(E + 255) / 256, 256, 0, stream>>>(esrc, edst, offs, dinv, cursor,
                                                          csr, E);

    dim3 pgrid((NPER + 127) / 128, NB);

    // layer 1
    gemm_kernel<<<(NODES + 63) / 64, 256, 0, stream>>>(x, W1, Hb, NODES, F_IN);
    agg_kernel<<<NODES, 64, 0, stream>>>(Hb, csr, offs, b1, Bu1);
    pool_kernel<<<pgrid, 128, 0, stream>>>(Bu1, pmask, pooled, NPER);
    // layer 2
    gemm_kernel<<<(NODES + 63) / 64, 256, 0, stream>>>(Bu1, W2, Hb, NODES, C);
    agg_kernel<<<NODES, 64, 0, stream>>>(Hb, csr, offs, b2, Bu2);
    pool_kernel<<<pgrid, 128, 0, stream>>>(Bu2, pmask, pooled, NPER);
    // layer 3
    gemm_kernel<<<(NODES + 63) / 64, 256, 0, stream>>>(Bu2, W3, Hb, NODES, C);
    agg_kernel<<<NODES, 64, 0, stream>>>(Hb, csr, offs, b3, Bu1);
    pool_kernel<<<pgrid, 128, 0, stream>>>(Bu1, pmask, pooled, NPER);

    mlp_kernel<<<1, 256, 0, stream>>>(pooled, lw1, lb1, lw2, lb2, lw3, lb3, lw4, lb4, out);
}

// Round 3
// 825.801 us; speedup vs baseline: 1.6323x; 1.0861x over previous
//
#include <hip/hip_runtime.h>
#include <hip/hip_bf16.h>
#include <cstdint>

#define F_IN 256
#define C 128

typedef short bf8_t __attribute__((ext_vector_type(8)));   // 8 bf16 bit-patterns (4 VGPRs)
typedef float f4_t  __attribute__((ext_vector_type(4)));

static inline size_t align256(size_t x) { return (x + 255) & ~(size_t)255; }

// ---------------- graph preprocessing ----------------

__global__ void deg_count_kernel(const int* __restrict__ dst, int* __restrict__ degc, int E) {
    int i = blockIdx.x * blockDim.x + threadIdx.x;
    if (i < E) atomicAdd(&degc[dst[i]], 1);
}

__global__ void dinv_kernel(const int* __restrict__ degc, float* __restrict__ dinv, int n) {
    int i = blockIdx.x * blockDim.x + threadIdx.x;
    if (i < n) dinv[i] = rsqrtf((float)degc[i] + 1.0f);
}

// Single-block exclusive scan of (degc[i]+1) -> offs[0..n], offs[n] = total.
__global__ __launch_bounds__(1024) void scan_kernel(const int* __restrict__ degc,
                                                    int* __restrict__ offs, int n) {
    __shared__ int sums[1024];
    int tid = threadIdx.x;
    int per = (n + 1023) >> 10;
    int s = tid * per, e = min(s + per, n);
    int loc = 0;
    for (int i = s; i < e; ++i) loc += degc[i] + 1;
    sums[tid] = loc;
    __syncthreads();
    for (int d = 1; d < 1024; d <<= 1) {
        int v = (tid >= d) ? sums[tid - d] : 0;
        __syncthreads();
        sums[tid] += v;
        __syncthreads();
    }
    int run = (tid == 0) ? 0 : sums[tid - 1];
    for (int i = s; i < e; ++i) { offs[i] = run; run += degc[i] + 1; }
    if (tid == 1023) offs[n] = run;
}

// Index-only CSR: self-loop entry first in each node's list.
__global__ void self_fill_kernel(const int* __restrict__ offs, int* __restrict__ csr, int n) {
    int i = blockIdx.x * blockDim.x + threadIdx.x;
    if (i < n) csr[offs[i]] = i;
}

__global__ void edge_fill_kernel(const int* __restrict__ src, const int* __restrict__ dst,
                                 const int* __restrict__ offs, int* __restrict__ cursor,
                                 int* __restrict__ csr, int E) {
    int e = blockIdx.x * blockDim.x + threadIdx.x;
    if (e < E) {
        int d = dst[e];
        int p = atomicAdd(&cursor[d], 1);
        csr[offs[d] + 1 + p] = src[e];
    }
}

// ---------------- x fp32 -> bf16 ----------------
__global__ void cvt_kernel(const float* __restrict__ x, __hip_bfloat16* __restrict__ xb, int n) {
    int i = (blockIdx.x * blockDim.x + threadIdx.x) * 4;
    if (i < n) {
        float4 v = *(const float4*)(x + i);
        __hip_bfloat162 lo = __float22bfloat162_rn(make_float2(v.x, v.y));
        __hip_bfloat162 hi = __float22bfloat162_rn(make_float2(v.z, v.w));
        uint2 o;
        o.x = *(unsigned*)&lo;
        o.y = *(unsigned*)&hi;
        *(uint2*)(xb + i) = o;
    }
}

// ---------------- W swizzle: fp32 [K,128] -> bf16 MFMA B-frag order ----------------
// entry id i = (t*8 + u)*64 + l  ->  8 bf16: W[t*32 + (l>>4)*8 + j][u*16 + (l&15)]
__global__ void wswz_kernel(const float* __restrict__ W, __hip_bfloat16* __restrict__ Wsw,
                            int K) {
    int i = blockIdx.x * blockDim.x + threadIdx.x;
    int total = (K >> 5) * 8 * 64;
    if (i < total) {
        int l = i & 63;
        int u = (i >> 6) & 7;
        int t = i >> 9;
        int krow = t * 32 + (l >> 4) * 8;
        int col = u * 16 + (l & 15);
        unsigned packed[4];
#pragma unroll
        for (int j = 0; j < 4; ++j) {
            float a = W[(size_t)(krow + 2 * j) * C + col];
            float b = W[(size_t)(krow + 2 * j + 1) * C + col];
            __hip_bfloat162 h = __float22bfloat162_rn(make_float2(a, b));
            packed[j] = *(unsigned*)&h;
        }
        uint4 o = make_uint4(packed[0], packed[1], packed[2], packed[3]);
        *(uint4*)(Wsw + (size_t)i * 8) = o;
    }
}

// ---------------- MFMA GEMM: G[M,128] = bf16( dinv[row] * (X[M,K] @ W) ) ----------------
// block: 256 threads = 4 waves, 128 rows; W (swizzled) resident in LDS; A direct from global.
__global__ __launch_bounds__(256) void mfma_gemm_kernel(const __hip_bfloat16* __restrict__ X,
                                                        const __hip_bfloat16* __restrict__ Wsw,
                                                        const float* __restrict__ dinv,
                                                        __hip_bfloat16* __restrict__ G,
                                                        int M, int K) {
    extern __shared__ char lds[];   // K*256 bytes
    const int tid = threadIdx.x;
    const int l = tid & 63;
    const int w = tid >> 6;
    const int lm = l & 15;
    const int lk = (l >> 4) * 8;
    const int row0 = blockIdx.x * 128 + w * 32;

    // stage swizzled W into LDS (contiguous copy)
    const int bytes = K * 256;
    for (int o = tid * 16; o < bytes; o += 256 * 16)
        *(uint4*)(lds + o) = *(const uint4*)((const char*)Wsw + o);
    __syncthreads();

    f4_t acc[2][8] = {};
    const int steps = K >> 5;
    const int r0 = min(row0 + lm, M - 1);
    const int r1 = min(row0 + 16 + lm, M - 1);
    const __hip_bfloat16* a0p = X + (size_t)r0 * K + lk;
    const __hip_bfloat16* a1p = X + (size_t)r1 * K + lk;

    for (int t = 0; t < steps; ++t) {
        bf8_t a0 = *(const bf8_t*)(a0p + t * 32);
        bf8_t a1 = *(const bf8_t*)(a1p + t * 32);
        const char* bbase = lds + ((size_t)(t * 8) * 64 + l) * 16;
#pragma unroll
        for (int u = 0; u < 8; ++u) {
            bf8_t b = *(const bf8_t*)(bbase + (size_t)u * 64 * 16);
            acc[0][u] = __builtin_amdgcn_mfma_f32_16x16x32_bf16(a0, b, acc[0][u], 0, 0, 0);
            acc[1][u] = __builtin_amdgcn_mfma_f32_16x16x32_bf16(a1, b, acc[1][u], 0, 0, 0);
        }
    }

    // epilogue: C/D map col=lane&15, row=(lane>>4)*4+reg; scale by dinv[row]
#pragma unroll
    for (int mt = 0; mt < 2; ++mt) {
        int rbase = row0 + mt * 16 + (l >> 4) * 4;
#pragma unroll
        for (int r = 0; r < 4; ++r) {
            int row = rbase + r;
            if (row < M) {
                float dv = dinv[row];
#pragma unroll
                for (int u = 0; u < 8; ++u) {
                    float v = acc[mt][u][r] * dv;
                    G[(size_t)row * C + u * 16 + lm] = __float2bfloat16(v);
                }
            }
        }
    }
}

// ---------------- aggregation: A[i] = relu(dinv[i]*sum_{j in csr[i]} G[j] + bias) ----------------
// one block (64 threads, 2 channels each) per node; pure gather-sum (coef factored out).
__global__ __launch_bounds__(64) void agg_kernel(const __hip_bfloat16* __restrict__ G,
                                                 const int* __restrict__ csr,
                                                 const int* __restrict__ offs,
                                                 const float* __restrict__ dinv,
                                                 const float* __restrict__ bias,
                                                 __hip_bfloat16* __restrict__ A) {
    __shared__ int s_i[64];
    const int node = blockIdx.x;
    const int tid = threadIdx.x;
    const int c0 = tid * 2;
    const int beg = offs[node], end = offs[node + 1];
    float accx = 0.f, accy = 0.f;
    for (int base = beg; base < end; base += 64) {
        int cnt = min(64, end - base);
        if (tid < cnt) s_i[tid] = csr[base + tid];
        __syncthreads();
#pragma unroll 4
        for (int j = 0; j < cnt; ++j) {
            __hip_bfloat162 hv = *(const __hip_bfloat162*)(G + (size_t)s_i[j] * C + c0);
            float2 f = __bfloat1622float2(hv);
            accx += f.x;
            accy += f.y;
        }
        __syncthreads();
    }
    float d = dinv[node];
    float ox = fmaxf(accx * d + bias[c0], 0.f);
    float oy = fmaxf(accy * d + bias[c0 + 1], 0.f);
    __hip_bfloat162 o = __float22bfloat162_rn(make_float2(ox, oy));
    *(__hip_bfloat162*)(A + (size_t)node * C + c0) = o;
}

// ---------------- masked pool accumulate: pooled[b,c] += sum_n mask*A ----------------
__global__ __launch_bounds__(128) void pool_kernel(const __hip_bfloat16* __restrict__ S,
                                                   const int* __restrict__ mask,
                                                   float* __restrict__ pooled, int N) {
    const int b = blockIdx.y;
    const int n0 = blockIdx.x * 128;
    const int c = threadIdx.x;
    const int lim = min(n0 + 128, N);
    float acc = 0.f;
    for (int n = n0; n < lim; ++n) {
        if (mask[b * N + n]) acc += __bfloat162float(S[((size_t)b * N + n) * C + c]);
    }
    atomicAdd(&pooled[b * C + c], acc);
}

// ---------------- MLP head: [4,128]->256->64->16->1 ----------------
__global__ __launch_bounds__(256) void mlp_kernel(const float* __restrict__ pooled,
        const float* __restrict__ lw1, const float* __restrict__ lb1,
        const float* __restrict__ lw2, const float* __restrict__ lb2,
        const float* __restrict__ lw3, const float* __restrict__ lb3,
        const float* __restrict__ lw4, const float* __restrict__ lb4,
        float* __restrict__ out) {
    __shared__ float p[4 * 128];
    __shared__ float z1[4 * 256];
    __shared__ float z2[4 * 64];
    __shared__ float z3[4 * 16];
    const int tid = threadIdx.x;
    for (int i = tid; i < 4 * 128; i += 256) p[i] = pooled[i];
    __syncthreads();
    for (int o = tid; o < 4 * 256; o += 256) {
        int b = o >> 8, j = o & 255;
        float s = lb1[j];
        for (int k = 0; k < 128; ++k) s += p[b * 128 + k] * lw1[k * 256 + j];
        z1[o] = fmaxf(s, 0.f);
    }
    __syncthreads();
    for (int o = tid; o < 4 * 64; o += 256) {
        int b = o >> 6, j = o & 63;
        float s = lb2[j];
        for (int k = 0; k < 256; ++k) s += z1[b * 256 + k] * lw2[k * 64 + j];
        z2[o] = fmaxf(s, 0.f);
    }
    __syncthreads();
    if (tid < 64) {
        int b = tid >> 4, j = tid & 15;
        float s = lb3[j];
        for (int k = 0; k < 64; ++k) s += z2[b * 64 + k] * lw3[k * 16 + j];
        z3[tid] = fmaxf(s, 0.f);
    }
    __syncthreads();
    if (tid < 4) {
        float s = lb4[0];
        for (int k = 0; k < 16; ++k) s += z3[tid * 16 + k] * lw4[k];
        out[tid] = s;
    }
}

// ---------------- launcher ----------------

extern "C" void kernel_launch(void* const* d_in, const int* in_sizes, int n_in,
                              void* d_out, int out_size, void* d_ws, size_t ws_size,
                              hipStream_t stream) {
    const float* x    = (const float*)d_in[0];
    const int*   ei   = (const int*)d_in[1];
    const int*   pmask = (const int*)d_in[2];
    const float* W1 = (const float*)d_in[3];  const float* b1 = (const float*)d_in[4];
    const float* W2 = (const float*)d_in[5];  const float* b2 = (const float*)d_in[6];
    const float* W3 = (const float*)d_in[7];  const float* b3 = (const float*)d_in[8];
    const float* lw1 = (const float*)d_in[9];  const float* lb1 = (const float*)d_in[10];
    const float* lw2 = (const float*)d_in[11]; const float* lb2 = (const float*)d_in[12];
    const float* lw3 = (const float*)d_in[13]; const float* lb3 = (const float*)d_in[14];
    const float* lw4 = (const float*)d_in[15]; const float* lb4 = (const float*)d_in[16];
    float* out = (float*)d_out;

    const int E = in_sizes[1] / 2;
    const int NODES = in_sizes[0] / F_IN;
    const int NB = 4;
    const int NPER = NODES / NB;   // 17000
    const int* esrc = ei;
    const int* edst = ei + E;

    char* w = (char*)d_ws;
    size_t off = 0;
    auto alloc = [&](size_t bytes) -> void* {
        void* p = w + off;
        off = align256(off + bytes);
        return p;
    };
    int*   degc   = (int*)  alloc((size_t)NODES * 4);
    float* dinv   = (float*)alloc((size_t)NODES * 4);
    int*   offs   = (int*)  alloc((size_t)(NODES + 1) * 4);
    int*   cursor = (int*)  alloc((size_t)NODES * 4);
    int*   csr    = (int*)  alloc((size_t)(E + NODES) * 4);
    __hip_bfloat16* Xb  = (__hip_bfloat16*)alloc((size_t)NODES * F_IN * 2);
    __hip_bfloat16* G   = (__hip_bfloat16*)alloc((size_t)NODES * C * 2);
    __hip_bfloat16* A1  = (__hip_bfloat16*)alloc((size_t)NODES * C * 2);
    __hip_bfloat16* A2  = (__hip_bfloat16*)alloc((size_t)NODES * C * 2);
    __hip_bfloat16* Wsw = (__hip_bfloat16*)alloc((size_t)F_IN * C * 2);
    float* pooled = (float*)alloc((size_t)4 * C * 4);
    (void)ws_size; (void)n_in; (void)out_size;

    hipMemsetAsync(degc,   0, (size_t)NODES * 4, stream);
    hipMemsetAsync(cursor, 0, (size_t)NODES * 4, stream);
    hipMemsetAsync(pooled, 0, (size_t)4 * C * 4, stream);

    deg_count_kernel<<<(E + 255) / 256, 256, 0, stream>>>(edst, degc, E);
    dinv_kernel<<<(NODES + 255) / 256, 256, 0, stream>>>(degc, dinv, NODES);
    scan_kernel<<<1, 1024, 0, stream>>>(degc, offs, NODES);
    self_fill_kernel<<<(NODES + 255) / 256, 256, 0, stream>>>(offs, csr, NODES);
    edge_fill_kernel<<<(E + 255) / 256, 256, 0, stream>>>(esrc, edst, offs, cursor, csr, E);
    cvt_kernel<<<(NODES * F_IN / 4 + 255) / 256, 256, 0, stream>>>(x, Xb, NODES * F_IN);

    const int gblocks = (NODES + 127) / 128;
    dim3 pgrid((NPER + 127) / 128, NB);

    // layer 1 (K = 256)
    wswz_kernel<<<(F_IN / 32 * 512 + 255) / 256, 256, 0, stream>>>(W1, Wsw, F_IN);
    mfma_gemm_kernel<<<gblocks, 256, F_IN * 256, stream>>>(Xb, Wsw, dinv, G, NODES, F_IN);
    agg_kernel<<<NODES, 64, 0, stream>>>(G, csr, offs, dinv, b1, A1);
    pool_kernel<<<pgrid, 128, 0, stream>>>(A1, pmask, pooled, NPER);
    // layer 2 (K = 128)
    wswz_kernel<<<(C / 32 * 512 + 255) / 256, 256, 0, stream>>>(W2, Wsw, C);
    mfma_gemm_kernel<<<gblocks, 256, C * 256, stream>>>(A1, Wsw, dinv, G, NODES, C);
    agg_kernel<<<NODES, 64, 0, stream>>>(G, csr, offs, dinv, b2, A2);
    pool_kernel<<<pgrid, 128, 0, stream>>>(A2, pmask, pooled, NPER);
    // layer 3 (K = 128)
    wswz_kernel<<<(C / 32 * 512 + 255) / 256, 256, 0, stream>>>(W3, Wsw, C);
    mfma_gemm_kernel<<<gblocks, 256, C * 256, stream>>>(A2, Wsw, dinv, G, NODES, C);
    agg_kernel<<<NODES, 64, 0, stream>>>(G, csr, offs, dinv, b3, A1);
    pool_kernel<<<pgrid, 128, 0, stream>>>(A1, pmask, pooled, NPER);

    mlp_kernel<<<1, 256, 0, stream>>>(pooled, lw1, lb1, lw2, lb2, lw3, lb3, lw4, lb4, out);
}

// Round 4
// 745.255 us; speedup vs baseline: 1.8087x; 1.1081x over previous
//
#include <hip/hip_runtime.h>
#include <hip/hip_bf16.h>
#include <cstdint>

#define F_IN 256
#define C 128
#define NBUK_MAX 320     // supports NODES <= 81920 (bucket = dst >> 8)
#define CHUNK 4096       // edges per partition block

typedef short bf8_t __attribute__((ext_vector_type(8)));   // 8 bf16 bit-patterns (4 VGPRs)
typedef float f4_t  __attribute__((ext_vector_type(4)));

static inline size_t align256(size_t x) { return (x + 255) & ~(size_t)255; }

// ---------------- graph preprocessing ----------------

__global__ void deg_count_kernel(const int* __restrict__ dst, int* __restrict__ degc, int E) {
    int i = blockIdx.x * blockDim.x + threadIdx.x;
    if (i < E) atomicAdd(&degc[dst[i]], 1);
}

__global__ void dinv_kernel(const int* __restrict__ degc, float* __restrict__ dinv, int n) {
    int i = blockIdx.x * blockDim.x + threadIdx.x;
    if (i < n) dinv[i] = rsqrtf((float)degc[i] + 1.0f);
}

// Single-block exclusive scan of (degc[i]+1) -> offs[0..n], offs[n] = total.
__global__ __launch_bounds__(1024) void scan_kernel(const int* __restrict__ degc,
                                                    int* __restrict__ offs, int n) {
    __shared__ int sums[1024];
    int tid = threadIdx.x;
    int per = (n + 1023) >> 10;
    int s = tid * per, e = min(s + per, n);
    int loc = 0;
    for (int i = s; i < e; ++i) loc += degc[i] + 1;
    sums[tid] = loc;
    __syncthreads();
    for (int d = 1; d < 1024; d <<= 1) {
        int v = (tid >= d) ? sums[tid - d] : 0;
        __syncthreads();
        sums[tid] += v;
        __syncthreads();
    }
    int run = (tid == 0) ? 0 : sums[tid - 1];
    for (int i = s; i < e; ++i) { offs[i] = run; run += degc[i] + 1; }
    if (tid == 1023) offs[n] = run;
}

// gcur[b] = start of bucket b's region in the edge-domain array (offs minus self-loops)
__global__ void init_gcur_kernel(const int* __restrict__ offs, int* __restrict__ gcur,
                                 int nodes, int nbuk) {
    int b = blockIdx.x * blockDim.x + threadIdx.x;
    if (b < nbuk) {
        int idx = min(b << 8, nodes);
        gcur[b] = offs[idx] - idx;
    }
}

// Pass 1: partition edges by bucket (dst>>8) with LDS staging -> grouped writes.
__global__ __launch_bounds__(256) void partition_kernel(const int* __restrict__ src,
                                                        const int* __restrict__ dst,
                                                        int* __restrict__ gcur,
                                                        int2* __restrict__ ebuf, int E) {
    __shared__ int hist[NBUK_MAX];
    __shared__ int base[NBUK_MAX];
    __shared__ int gbase[NBUK_MAX];
    __shared__ int2 stage[CHUNK];
    const int tid = threadIdx.x;
    const int e0 = blockIdx.x * CHUNK;
    const int cnt = min(CHUNK, E - e0);

    for (int i = tid; i < NBUK_MAX; i += 256) hist[i] = 0;
    __syncthreads();

    int2 ev[CHUNK / 256];
    int mo[CHUNK / 256];
#pragma unroll
    for (int k = 0; k < CHUNK / 256; ++k) {
        int e = e0 + k * 256 + tid;
        if (e < E) {
            int2 v;
            v.x = src[e];
            v.y = dst[e];
            ev[k] = v;
            mo[k] = atomicAdd(&hist[v.y >> 8], 1);
        }
    }
    __syncthreads();
    // exclusive scan of hist (320 entries) by wave 0: 5 buckets/lane + shuffle scan
    if (tid < 64) {
        int acc[5];
        int s = 0;
#pragma unroll
        for (int j = 0; j < 5; ++j) {
            int idx = tid * 5 + j;
            acc[j] = s;
            s += hist[idx];
        }
        int tot = s;
#pragma unroll
        for (int d = 1; d < 64; d <<= 1) {
            int o = __shfl_up(tot, d);
            if (tid >= d) tot += o;
        }
        int excl = tot - s;
#pragma unroll
        for (int j = 0; j < 5; ++j) base[tid * 5 + j] = excl + acc[j];
    }
    __syncthreads();
    // reserve global ranges (one atomic per nonempty bucket)
    for (int i = tid; i < NBUK_MAX; i += 256) {
        int h = hist[i];
        gbase[i] = h ? atomicAdd(&gcur[i], h) : 0;
    }
    __syncthreads();
    // scatter into LDS staging grouped by bucket
#pragma unroll
    for (int k = 0; k < CHUNK / 256; ++k) {
        int e = e0 + k * 256 + tid;
        if (e < E) stage[base[ev[k].y >> 8] + mo[k]] = ev[k];
    }
    __syncthreads();
    // grouped write-out: consecutive staged entries -> consecutive global slots
    for (int i = tid; i < cnt; i += 256) {
        int2 e = stage[i];
        int b = e.y >> 8;
        ebuf[gbase[b] + (i - base[b])] = e;
    }
}

// Pass 2: per-bucket CSR build (LDS cursors, writes confined to a ~36KB window).
// Also writes the self-loop entry at the head of each node's list.
__global__ __launch_bounds__(256) void csr_build_kernel(const int2* __restrict__ ebuf,
                                                        const int* __restrict__ offs,
                                                        int* __restrict__ csr, int nodes) {
    __shared__ int cur[256];
    __shared__ int soffs[257];
    const int b = blockIdx.x;
    const int n0 = b << 8;
    const int ncnt = min(256, nodes - n0);
    const int tid = threadIdx.x;
    cur[tid] = 0;
    for (int i = tid; i <= ncnt; i += 256) soffs[i] = offs[n0 + i];
    __syncthreads();
    const int ebeg = soffs[0] - n0;
    const int eend = soffs[ncnt] - (n0 + ncnt);
    for (int i = ebeg + tid; i < eend; i += 256) {
        int2 e = ebuf[i];
        int loc = e.y - n0;
        int p = atomicAdd(&cur[loc], 1);
        csr[soffs[loc] + 1 + p] = e.x;
    }
    if (tid < ncnt) csr[soffs[tid]] = n0 + tid;
}

// ---------------- W swizzle: fp32 [K,128] -> bf16 MFMA B-frag order ----------------
// entry id i = (t*8 + u)*64 + l  ->  8 bf16: W[t*32 + (l>>4)*8 + j][u*16 + (l&15)]
static __device__ inline unsigned pack_bf16(float a, float b) {
    __hip_bfloat162 h = __float22bfloat162_rn(make_float2(a, b));
    return *(unsigned*)&h;
}

__global__ void wswz_kernel(const float* __restrict__ W, __hip_bfloat16* __restrict__ Wsw,
                            int K) {
    int i = blockIdx.x * blockDim.x + threadIdx.x;
    int total = (K >> 5) * 8 * 64;
    if (i < total) {
        int l = i & 63;
        int u = (i >> 6) & 7;
        int t = i >> 9;
        int krow = t * 32 + (l >> 4) * 8;
        int col = u * 16 + (l & 15);
        unsigned packed[4];
#pragma unroll
        for (int j = 0; j < 4; ++j) {
            float a = W[(size_t)(krow + 2 * j) * C + col];
            float b = W[(size_t)(krow + 2 * j + 1) * C + col];
            packed[j] = pack_bf16(a, b);
        }
        uint4 o = make_uint4(packed[0], packed[1], packed[2], packed[3]);
        *(uint4*)(Wsw + (size_t)i * 8) = o;
    }
}

// ---------------- MFMA GEMM: G[M,128] = bf16( dinv[row] * (X[M,K] @ W) ) ----------------
// block: 256 threads = 4 waves, 128 rows; W (swizzled) resident in LDS.

static __device__ inline bf8_t pack8(float4 u0, float4 u1) {
    union { unsigned u[4]; bf8_t v; } r;
    r.u[0] = pack_bf16(u0.x, u0.y);
    r.u[1] = pack_bf16(u0.z, u0.w);
    r.u[2] = pack_bf16(u1.x, u1.y);
    r.u[3] = pack_bf16(u1.z, u1.w);
    return r.v;
}

template <bool F32IN>
__global__ __launch_bounds__(256) void mfma_gemm_kernel(const void* __restrict__ Xv,
                                                        const __hip_bfloat16* __restrict__ Wsw,
                                                        const float* __restrict__ dinv,
                                                        __hip_bfloat16* __restrict__ G,
                                                        int M, int K) {
    extern __shared__ char lds[];   // K*256 bytes
    const int tid = threadIdx.x;
    const int l = tid & 63;
    const int w = tid >> 6;
    const int lm = l & 15;
    const int lk = (l >> 4) * 8;
    const int row0 = blockIdx.x * 128 + w * 32;

    const int bytes = K * 256;
    for (int o = tid * 16; o < bytes; o += 256 * 16)
        *(uint4*)(lds + o) = *(const uint4*)((const char*)Wsw + o);
    __syncthreads();

    f4_t acc[2][8] = {};
    const int steps = K >> 5;
    const int r0 = min(row0 + lm, M - 1);
    const int r1 = min(row0 + 16 + lm, M - 1);

    const float* xf0 = (const float*)Xv + (size_t)r0 * K + lk;
    const float* xf1 = (const float*)Xv + (size_t)r1 * K + lk;
    const __hip_bfloat16* xb0 = (const __hip_bfloat16*)Xv + (size_t)r0 * K + lk;
    const __hip_bfloat16* xb1 = (const __hip_bfloat16*)Xv + (size_t)r1 * K + lk;

    for (int t = 0; t < steps; ++t) {
        bf8_t a0, a1;
        if (F32IN) {
            float4 u0 = *(const float4*)(xf0 + t * 32);
            float4 u1 = *(const float4*)(xf0 + t * 32 + 4);
            float4 v0 = *(const float4*)(xf1 + t * 32);
            float4 v1 = *(const float4*)(xf1 + t * 32 + 4);
            a0 = pack8(u0, u1);
            a1 = pack8(v0, v1);
        } else {
            a0 = *(const bf8_t*)(xb0 + t * 32);
            a1 = *(const bf8_t*)(xb1 + t * 32);
        }
        const char* bbase = lds + ((size_t)(t * 8) * 64 + l) * 16;
#pragma unroll
        for (int u = 0; u < 8; ++u) {
            bf8_t b = *(const bf8_t*)(bbase + (size_t)u * 64 * 16);
            acc[0][u] = __builtin_amdgcn_mfma_f32_16x16x32_bf16(a0, b, acc[0][u], 0, 0, 0);
            acc[1][u] = __builtin_amdgcn_mfma_f32_16x16x32_bf16(a1, b, acc[1][u], 0, 0, 0);
        }
    }

    // epilogue: C/D map col=lane&15, row=(lane>>4)*4+reg; scale by dinv[row]
#pragma unroll
    for (int mt = 0; mt < 2; ++mt) {
        int rbase = row0 + mt * 16 + (l >> 4) * 4;
#pragma unroll
        for (int r = 0; r < 4; ++r) {
            int row = rbase + r;
            if (row < M) {
                float dv = dinv[row];
#pragma unroll
                for (int u = 0; u < 8; ++u) {
                    float v = acc[mt][u][r] * dv;
                    G[(size_t)row * C + u * 16 + lm] = __float2bfloat16(v);
                }
            }
        }
    }
}

// ---------------- aggregation: A[i] = relu(dinv[i]*sum_{j in csr[i]} G[j] + bias) ----------------
__global__ __launch_bounds__(64) void agg_kernel(const __hip_bfloat16* __restrict__ G,
                                                 const int* __restrict__ csr,
                                                 const int* __restrict__ offs,
                                                 const float* __restrict__ dinv,
                                                 const float* __restrict__ bias,
                                                 __hip_bfloat16* __restrict__ A) {
    __shared__ int s_i[64];
    const int node = blockIdx.x;
    const int tid = threadIdx.x;
    const int c0 = tid * 2;
    const int beg = offs[node], end = offs[node + 1];
    float accx = 0.f, accy = 0.f;
    for (int base = beg; base < end; base += 64) {
        int cnt = min(64, end - base);
        if (tid < cnt) s_i[tid] = csr[base + tid];
        __syncthreads();
#pragma unroll 4
        for (int j = 0; j < cnt; ++j) {
            __hip_bfloat162 hv = *(const __hip_bfloat162*)(G + (size_t)s_i[j] * C + c0);
            float2 f = __bfloat1622float2(hv);
            accx += f.x;
            accy += f.y;
        }
        __syncthreads();
    }
    float d = dinv[node];
    float ox = fmaxf(accx * d + bias[c0], 0.f);
    float oy = fmaxf(accy * d + bias[c0 + 1], 0.f);
    __hip_bfloat162 o = __float22bfloat162_rn(make_float2(ox, oy));
    *(__hip_bfloat162*)(A + (size_t)node * C + c0) = o;
}

// ---------------- masked pool accumulate: pooled[b,c] += sum_n mask*A ----------------
__global__ __launch_bounds__(64) void pool_kernel(const __hip_bfloat16* __restrict__ S,
                                                  const int* __restrict__ mask,
                                                  float* __restrict__ pooled, int N) {
    const int b = blockIdx.y;
    const int n0 = blockIdx.x * 128;
    const int c0 = threadIdx.x * 2;
    const int lim = min(n0 + 128, N);
    float ax = 0.f, ay = 0.f;
    for (int n = n0; n < lim; ++n) {
        if (mask[b * N + n]) {
            __hip_bfloat162 hv = *(const __hip_bfloat162*)(S + ((size_t)b * N + n) * C + c0);
            float2 f = __bfloat1622float2(hv);
            ax += f.x;
            ay += f.y;
        }
    }
    atomicAdd(&pooled[b * C + c0], ax);
    atomicAdd(&pooled[b * C + c0 + 1], ay);
}

// ---------------- MLP head: [4,128]->256->64->16->1 ----------------
__global__ __launch_bounds__(256) void mlp_kernel(const float* __restrict__ pooled,
        const float* __restrict__ lw1, const float* __restrict__ lb1,
        const float* __restrict__ lw2, const float* __restrict__ lb2,
        const float* __restrict__ lw3, const float* __restrict__ lb3,
        const float* __restrict__ lw4, const float* __restrict__ lb4,
        float* __restrict__ out) {
    __shared__ float p[4 * 128];
    __shared__ float z1[4 * 256];
    __shared__ float z2[4 * 64];
    __shared__ float z3[4 * 16];
    const int tid = threadIdx.x;
    for (int i = tid; i < 4 * 128; i += 256) p[i] = pooled[i];
    __syncthreads();
    for (int o = tid; o < 4 * 256; o += 256) {
        int b = o >> 8, j = o & 255;
        float s = lb1[j];
        for (int k = 0; k < 128; ++k) s += p[b * 128 + k] * lw1[k * 256 + j];
        z1[o] = fmaxf(s, 0.f);
    }
    __syncthreads();
    for (int o = tid; o < 4 * 64; o += 256) {
        int b = o >> 6, j = o & 63;
        float s = lb2[j];
        for (int k = 0; k < 256; ++k) s += z1[b * 256 + k] * lw2[k * 64 + j];
        z2[o] = fmaxf(s, 0.f);
    }
    __syncthreads();
    if (tid < 64) {
        int b = tid >> 4, j = tid & 15;
        float s = lb3[j];
        for (int k = 0; k < 64; ++k) s += z2[b * 64 + k] * lw3[k * 16 + j];
        z3[tid] = fmaxf(s, 0.f);
    }
    __syncthreads();
    if (tid < 4) {
        float s = lb4[0];
        for (int k = 0; k < 16; ++k) s += z3[tid * 16 + k] * lw4[k];
        out[tid] = s;
    }
}

// ---------------- launcher ----------------

extern "C" void kernel_launch(void* const* d_in, const int* in_sizes, int n_in,
                              void* d_out, int out_size, void* d_ws, size_t ws_size,
                              hipStream_t stream) {
    const float* x    = (const float*)d_in[0];
    const int*   ei   = (const int*)d_in[1];
    const int*   pmask = (const int*)d_in[2];
    const float* W1 = (const float*)d_in[3];  const float* b1 = (const float*)d_in[4];
    const float* W2 = (const float*)d_in[5];  const float* b2 = (const float*)d_in[6];
    const float* W3 = (const float*)d_in[7];  const float* b3 = (const float*)d_in[8];
    const float* lw1 = (const float*)d_in[9];  const float* lb1 = (const float*)d_in[10];
    const float* lw2 = (const float*)d_in[11]; const float* lb2 = (const float*)d_in[12];
    const float* lw3 = (const float*)d_in[13]; const float* lb3 = (const float*)d_in[14];
    const float* lw4 = (const float*)d_in[15]; const float* lb4 = (const float*)d_in[16];
    float* out = (float*)d_out;

    const int E = in_sizes[1] / 2;
    const int NODES = in_sizes[0] / F_IN;
    const int NB = 4;
    const int NPER = NODES / NB;   // 17000
    const int NBUK = (NODES + 255) >> 8;
    const int* esrc = ei;
    const int* edst = ei + E;

    char* w = (char*)d_ws;
    size_t off = 0;
    auto alloc = [&](size_t bytes) -> void* {
        void* p = w + off;
        off = align256(off + bytes);
        return p;
    };
    int*   degc = (int*)  alloc((size_t)NODES * 4);
    float* dinv = (float*)alloc((size_t)NODES * 4);
    int*   offs = (int*)  alloc((size_t)(NODES + 1) * 4);
    int*   gcur = (int*)  alloc((size_t)NBUK * 4);
    int2*  ebuf = (int2*) alloc((size_t)E * 8);
    int*   csr  = (int*)  alloc((size_t)(E + NODES) * 4);
    __hip_bfloat16* G   = (__hip_bfloat16*)alloc((size_t)NODES * C * 2);
    __hip_bfloat16* A1  = (__hip_bfloat16*)alloc((size_t)NODES * C * 2);
    __hip_bfloat16* A2  = (__hip_bfloat16*)alloc((size_t)NODES * C * 2);
    __hip_bfloat16* Wsw = (__hip_bfloat16*)alloc((size_t)F_IN * C * 2);
    float* pooled = (float*)alloc((size_t)4 * C * 4);
    (void)ws_size; (void)n_in; (void)out_size;

    hipMemsetAsync(degc,   0, (size_t)NODES * 4, stream);
    hipMemsetAsync(pooled, 0, (size_t)4 * C * 4, stream);

    deg_count_kernel<<<(E + 255) / 256, 256, 0, stream>>>(edst, degc, E);
    dinv_kernel<<<(NODES + 255) / 256, 256, 0, stream>>>(degc, dinv, NODES);
    scan_kernel<<<1, 1024, 0, stream>>>(degc, offs, NODES);
    init_gcur_kernel<<<(NBUK + 255) / 256, 256, 0, stream>>>(offs, gcur, NODES, NBUK);
    partition_kernel<<<(E + CHUNK - 1) / CHUNK, 256, 0, stream>>>(esrc, edst, gcur, ebuf, E);
    csr_build_kernel<<<NBUK, 256, 0, stream>>>(ebuf, offs, csr, NODES);

    const int gblocks = (NODES + 127) / 128;
    dim3 pgrid((NPER + 127) / 128, NB);

    // layer 1 (K = 256, fp32 input fused-converted)
    wswz_kernel<<<(F_IN / 32 * 512 + 255) / 256, 256, 0, stream>>>(W1, Wsw, F_IN);
    mfma_gemm_kernel<true><<<gblocks, 256, F_IN * 256, stream>>>(x, Wsw, dinv, G, NODES, F_IN);
    agg_kernel<<<NODES, 64, 0, stream>>>(G, csr, offs, dinv, b1, A1);
    pool_kernel<<<pgrid, 64, 0, stream>>>(A1, pmask, pooled, NPER);
    // layer 2 (K = 128)
    wswz_kernel<<<(C / 32 * 512 + 255) / 256, 256, 0, stream>>>(W2, Wsw, C);
    mfma_gemm_kernel<false><<<gblocks, 256, C * 256, stream>>>(A1, Wsw, dinv, G, NODES, C);
    agg_kernel<<<NODES, 64, 0, stream>>>(G, csr, offs, dinv, b2, A2);
    pool_kernel<<<pgrid, 64, 0, stream>>>(A2, pmask, pooled, NPER);
    // layer 3 (K = 128)
    wswz_kernel<<<(C / 32 * 512 + 255) / 256, 256, 0, stream>>>(W3, Wsw, C);
    mfma_gemm_kernel<false><<<gblocks, 256, C * 256, stream>>>(A2, Wsw, dinv, G, NODES, C);
    agg_kernel<<<NODES, 64, 0, stream>>>(G, csr, offs, dinv, b3, A1);
    pool_kernel<<<pgrid, 64, 0, stream>>>(A1, pmask, pooled, NPER);

    mlp_kernel<<<1, 256, 0, stream>>>(pooled, lw1, lb1, lw2, lb2, lw3, lb3, lw4, lb4, out);
}

// Round 5
// 653.039 us; speedup vs baseline: 2.0641x; 1.1412x over previous
//
#include <hip/hip_runtime.h>
#include <hip/hip_bf16.h>
#include <cstdint>

#define F_IN 256
#define C 128
#define NBUK_MAX 320     // supports NODES <= 81920 (bucket = dst >> 8)
#define CHUNK 4096       // edges per partition block
#define SCAN_TILE 2048   // elements per scan block

typedef short bf8_t __attribute__((ext_vector_type(8)));   // 8 bf16 bit-patterns (4 VGPRs)
typedef float f4_t  __attribute__((ext_vector_type(4)));

static inline size_t align256(size_t x) { return (x + 255) & ~(size_t)255; }

// ---------------- graph preprocessing ----------------

__global__ void deg_count_kernel(const int* __restrict__ dst, int* __restrict__ degc, int E) {
    int i = blockIdx.x * blockDim.x + threadIdx.x;
    if (i < E) atomicAdd(&degc[dst[i]], 1);
}

// ---- multi-block exclusive scan of (degc[i]+1), i in [0,n); offs[0..n] ----
// S1: per-block sums
__global__ __launch_bounds__(256) void scan1_kernel(const int* __restrict__ degc,
                                                    int* __restrict__ bsum, int n) {
    __shared__ int red[256];
    const int tid = threadIdx.x;
    const int start = blockIdx.x * SCAN_TILE;
    int s = 0;
#pragma unroll
    for (int j = 0; j < 8; ++j) {
        int i = start + tid * 8 + j;
        if (i < n) s += degc[i] + 1;
    }
    red[tid] = s;
    __syncthreads();
    for (int d = 128; d > 0; d >>= 1) {
        if (tid < d) red[tid] += red[tid + d];
        __syncthreads();
    }
    if (tid == 0) bsum[blockIdx.x] = red[0];
}

// S2: single-block scan of block sums (nb <= 256)
__global__ __launch_bounds__(256) void scan2_kernel(const int* __restrict__ bsum,
                                                    int* __restrict__ bpre, int nb) {
    __shared__ int p[256];
    const int tid = threadIdx.x;
    p[tid] = (tid < nb) ? bsum[tid] : 0;
    __syncthreads();
    for (int d = 1; d < 256; d <<= 1) {
        int v = (tid >= d) ? p[tid - d] : 0;
        __syncthreads();
        p[tid] += v;
        __syncthreads();
    }
    if (tid < nb) bpre[tid] = (tid == 0) ? 0 : p[tid - 1];
}

// S3: local scan + block prefix -> offs; fused dinv and gcur init.
__global__ __launch_bounds__(256) void scan3_kernel(const int* __restrict__ degc,
                                                    const int* __restrict__ bpre,
                                                    int* __restrict__ offs,
                                                    float* __restrict__ dinv,
                                                    int* __restrict__ gcur, int n) {
    __shared__ int part[256];
    const int tid = threadIdx.x;
    const int start = blockIdx.x * SCAN_TILE;
    const int base = start + tid * 8;
    int vals[8];
    int s = 0;
#pragma unroll
    for (int j = 0; j < 8; ++j) {
        int i = base + j;
        vals[j] = s;
        if (i < n) {
            int dv = degc[i] + 1;
            s += dv;
            dinv[i] = rsqrtf((float)dv);
        }
    }
    part[tid] = s;
    __syncthreads();
    for (int d = 1; d < 256; d <<= 1) {
        int v = (tid >= d) ? part[tid - d] : 0;
        __syncthreads();
        part[tid] += v;
        __syncthreads();
    }
    const int excl = ((tid == 0) ? 0 : part[tid - 1]) + bpre[blockIdx.x];
#pragma unroll
    for (int j = 0; j < 8; ++j) {
        int i = base + j;
        if (i <= n) {
            int o = excl + vals[j];
            offs[i] = o;
            if (i < n && (i & 255) == 0) gcur[i >> 8] = o - i;   // bucket start in edge domain
        }
    }
}

// Pass 1: partition edges by bucket (dst>>8) with LDS staging -> grouped writes.
__global__ __launch_bounds__(256) void partition_kernel(const int* __restrict__ src,
                                                        const int* __restrict__ dst,
                                                        int* __restrict__ gcur,
                                                        int2* __restrict__ ebuf, int E) {
    __shared__ int hist[NBUK_MAX];
    __shared__ int base[NBUK_MAX];
    __shared__ int gbase[NBUK_MAX];
    __shared__ int2 stage[CHUNK];
    const int tid = threadIdx.x;
    const int e0 = blockIdx.x * CHUNK;
    const int cnt = min(CHUNK, E - e0);

    for (int i = tid; i < NBUK_MAX; i += 256) hist[i] = 0;
    __syncthreads();

    int2 ev[CHUNK / 256];
    int mo[CHUNK / 256];
#pragma unroll
    for (int k = 0; k < CHUNK / 256; ++k) {
        int e = e0 + k * 256 + tid;
        if (e < E) {
            int2 v;
            v.x = src[e];
            v.y = dst[e];
            ev[k] = v;
            mo[k] = atomicAdd(&hist[v.y >> 8], 1);
        }
    }
    __syncthreads();
    // exclusive scan of hist (320 entries) by wave 0: 5 buckets/lane + shuffle scan
    if (tid < 64) {
        int acc[5];
        int s = 0;
#pragma unroll
        for (int j = 0; j < 5; ++j) {
            int idx = tid * 5 + j;
            acc[j] = s;
            s += hist[idx];
        }
        int tot = s;
#pragma unroll
        for (int d = 1; d < 64; d <<= 1) {
            int o = __shfl_up(tot, d);
            if (tid >= d) tot += o;
        }
        int excl = tot - s;
#pragma unroll
        for (int j = 0; j < 5; ++j) base[tid * 5 + j] = excl + acc[j];
    }
    __syncthreads();
    // reserve global ranges (one atomic per nonempty bucket)
    for (int i = tid; i < NBUK_MAX; i += 256) {
        int h = hist[i];
        gbase[i] = h ? atomicAdd(&gcur[i], h) : 0;
    }
    __syncthreads();
    // scatter into LDS staging grouped by bucket
#pragma unroll
    for (int k = 0; k < CHUNK / 256; ++k) {
        int e = e0 + k * 256 + tid;
        if (e < E) stage[base[ev[k].y >> 8] + mo[k]] = ev[k];
    }
    __syncthreads();
    // grouped write-out: consecutive staged entries -> consecutive global slots
    for (int i = tid; i < cnt; i += 256) {
        int2 e = stage[i];
        int b = e.y >> 8;
        ebuf[gbase[b] + (i - base[b])] = e;
    }
}

// Pass 2: per-bucket CSR build (LDS cursors, writes confined to a ~36KB window).
// Also writes the self-loop entry at the head of each node's list.
__global__ __launch_bounds__(256) void csr_build_kernel(const int2* __restrict__ ebuf,
                                                        const int* __restrict__ offs,
                                                        int* __restrict__ csr, int nodes) {
    __shared__ int cur[256];
    __shared__ int soffs[257];
    const int b = blockIdx.x;
    const int n0 = b << 8;
    const int ncnt = min(256, nodes - n0);
    const int tid = threadIdx.x;
    cur[tid] = 0;
    for (int i = tid; i <= ncnt; i += 256) soffs[i] = offs[n0 + i];
    __syncthreads();
    const int ebeg = soffs[0] - n0;
    const int eend = soffs[ncnt] - (n0 + ncnt);
    for (int i = ebeg + tid; i < eend; i += 256) {
        int2 e = ebuf[i];
        int loc = e.y - n0;
        int p = atomicAdd(&cur[loc], 1);
        csr[soffs[loc] + 1 + p] = e.x;
    }
    if (tid < ncnt) csr[soffs[tid]] = n0 + tid;
}

// ---------------- W swizzle: fp32 [K,128] -> bf16 MFMA B-frag order ----------------
// entry id i = (t*8 + u)*64 + l  ->  8 bf16: W[t*32 + (l>>4)*8 + j][u*16 + (l&15)]
static __device__ inline unsigned pack_bf16(float a, float b) {
    __hip_bfloat162 h = __float22bfloat162_rn(make_float2(a, b));
    return *(unsigned*)&h;
}

__global__ void wswz_kernel(const float* __restrict__ W, __hip_bfloat16* __restrict__ Wsw,
                            int K) {
    int i = blockIdx.x * blockDim.x + threadIdx.x;
    int total = (K >> 5) * 8 * 64;
    if (i < total) {
        int l = i & 63;
        int u = (i >> 6) & 7;
        int t = i >> 9;
        int krow = t * 32 + (l >> 4) * 8;
        int col = u * 16 + (l & 15);
        unsigned packed[4];
#pragma unroll
        for (int j = 0; j < 4; ++j) {
            float a = W[(size_t)(krow + 2 * j) * C + col];
            float b = W[(size_t)(krow + 2 * j + 1) * C + col];
            packed[j] = pack_bf16(a, b);
        }
        uint4 o = make_uint4(packed[0], packed[1], packed[2], packed[3]);
        *(uint4*)(Wsw + (size_t)i * 8) = o;
    }
}

// ---------------- MFMA GEMM: G[M,128] = bf16( dinv[row] * (X[M,K] @ W) ) ----------------
// block: 256 threads = 4 waves, 128 rows; W (swizzled) resident in LDS.

static __device__ inline bf8_t pack8(float4 u0, float4 u1) {
    union { unsigned u[4]; bf8_t v; } r;
    r.u[0] = pack_bf16(u0.x, u0.y);
    r.u[1] = pack_bf16(u0.z, u0.w);
    r.u[2] = pack_bf16(u1.x, u1.y);
    r.u[3] = pack_bf16(u1.z, u1.w);
    return r.v;
}

template <bool F32IN>
__global__ __launch_bounds__(256) void mfma_gemm_kernel(const void* __restrict__ Xv,
                                                        const __hip_bfloat16* __restrict__ Wsw,
                                                        const float* __restrict__ dinv,
                                                        __hip_bfloat16* __restrict__ G,
                                                        int M, int K) {
    extern __shared__ char lds[];   // K*256 bytes
    const int tid = threadIdx.x;
    const int l = tid & 63;
    const int w = tid >> 6;
    const int lm = l & 15;
    const int lk = (l >> 4) * 8;
    const int row0 = blockIdx.x * 128 + w * 32;

    const int bytes = K * 256;
    for (int o = tid * 16; o < bytes; o += 256 * 16)
        *(uint4*)(lds + o) = *(const uint4*)((const char*)Wsw + o);
    __syncthreads();

    f4_t acc[2][8] = {};
    const int steps = K >> 5;
    const int r0 = min(row0 + lm, M - 1);
    const int r1 = min(row0 + 16 + lm, M - 1);

    const float* xf0 = (const float*)Xv + (size_t)r0 * K + lk;
    const float* xf1 = (const float*)Xv + (size_t)r1 * K + lk;
    const __hip_bfloat16* xb0 = (const __hip_bfloat16*)Xv + (size_t)r0 * K + lk;
    const __hip_bfloat16* xb1 = (const __hip_bfloat16*)Xv + (size_t)r1 * K + lk;

    for (int t = 0; t < steps; ++t) {
        bf8_t a0, a1;
        if (F32IN) {
            float4 u0 = *(const float4*)(xf0 + t * 32);
            float4 u1 = *(const float4*)(xf0 + t * 32 + 4);
            float4 v0 = *(const float4*)(xf1 + t * 32);
            float4 v1 = *(const float4*)(xf1 + t * 32 + 4);
            a0 = pack8(u0, u1);
            a1 = pack8(v0, v1);
        } else {
            a0 = *(const bf8_t*)(xb0 + t * 32);
            a1 = *(const bf8_t*)(xb1 + t * 32);
        }
        const char* bbase = lds + ((size_t)(t * 8) * 64 + l) * 16;
#pragma unroll
        for (int u = 0; u < 8; ++u) {
            bf8_t b = *(const bf8_t*)(bbase + (size_t)u * 64 * 16);
            acc[0][u] = __builtin_amdgcn_mfma_f32_16x16x32_bf16(a0, b, acc[0][u], 0, 0, 0);
            acc[1][u] = __builtin_amdgcn_mfma_f32_16x16x32_bf16(a1, b, acc[1][u], 0, 0, 0);
        }
    }

    // epilogue: C/D map col=lane&15, row=(lane>>4)*4+reg; scale by dinv[row]
#pragma unroll
    for (int mt = 0; mt < 2; ++mt) {
        int rbase = row0 + mt * 16 + (l >> 4) * 4;
#pragma unroll
        for (int r = 0; r < 4; ++r) {
            int row = rbase + r;
            if (row < M) {
                float dv = dinv[row];
#pragma unroll
                for (int u = 0; u < 8; ++u) {
                    float v = acc[mt][u][r] * dv;
                    G[(size_t)row * C + u * 16 + lm] = __float2bfloat16(v);
                }
            }
        }
    }
}

// ---------------- aggregation: A[i] = relu(dinv[i]*sum_{j in csr[i]} G[j] + bias) ----------------
__global__ __launch_bounds__(64) void agg_kernel(const __hip_bfloat16* __restrict__ G,
                                                 const int* __restrict__ csr,
                                                 const int* __restrict__ offs,
                                                 const float* __restrict__ dinv,
                                                 const float* __restrict__ bias,
                                                 __hip_bfloat16* __restrict__ A) {
    __shared__ int s_i[64];
    const int node = blockIdx.x;
    const int tid = threadIdx.x;
    const int c0 = tid * 2;
    const int beg = offs[node], end = offs[node + 1];
    float accx = 0.f, accy = 0.f;
    for (int base = beg; base < end; base += 64) {
        int cnt = min(64, end - base);
        if (tid < cnt) s_i[tid] = csr[base + tid];
        __syncthreads();
#pragma unroll 4
        for (int j = 0; j < cnt; ++j) {
            __hip_bfloat162 hv = *(const __hip_bfloat162*)(G + (size_t)s_i[j] * C + c0);
            float2 f = __bfloat1622float2(hv);
            accx += f.x;
            accy += f.y;
        }
        __syncthreads();
    }
    float d = dinv[node];
    float ox = fmaxf(accx * d + bias[c0], 0.f);
    float oy = fmaxf(accy * d + bias[c0 + 1], 0.f);
    __hip_bfloat162 o = __float22bfloat162_rn(make_float2(ox, oy));
    *(__hip_bfloat162*)(A + (size_t)node * C + c0) = o;
}

// ---------------- masked pool accumulate: pooled[b,c] += sum_n mask*A ----------------
__global__ __launch_bounds__(64) void pool_kernel(const __hip_bfloat16* __restrict__ S,
                                                  const int* __restrict__ mask,
                                                  float* __restrict__ pooled, int N) {
    const int b = blockIdx.y;
    const int n0 = blockIdx.x * 128;
    const int c0 = threadIdx.x * 2;
    const int lim = min(n0 + 128, N);
    float ax = 0.f, ay = 0.f;
    for (int n = n0; n < lim; ++n) {
        if (mask[b * N + n]) {
            __hip_bfloat162 hv = *(const __hip_bfloat162*)(S + ((size_t)b * N + n) * C + c0);
            float2 f = __bfloat1622float2(hv);
            ax += f.x;
            ay += f.y;
        }
    }
    atomicAdd(&pooled[b * C + c0], ax);
    atomicAdd(&pooled[b * C + c0 + 1], ay);
}

// ---------------- MLP head: [4,128]->256->64->16->1 ----------------
__global__ __launch_bounds__(256) void mlp_kernel(const float* __restrict__ pooled,
        const float* __restrict__ lw1, const float* __restrict__ lb1,
        const float* __restrict__ lw2, const float* __restrict__ lb2,
        const float* __restrict__ lw3, const float* __restrict__ lb3,
        const float* __restrict__ lw4, const float* __restrict__ lb4,
        float* __restrict__ out) {
    __shared__ float p[4 * 128];
    __shared__ float z1[4 * 256];
    __shared__ float z2[4 * 64];
    __shared__ float z3[4 * 16];
    const int tid = threadIdx.x;
    for (int i = tid; i < 4 * 128; i += 256) p[i] = pooled[i];
    __syncthreads();
    for (int o = tid; o < 4 * 256; o += 256) {
        int b = o >> 8, j = o & 255;
        float s = lb1[j];
        for (int k = 0; k < 128; ++k) s += p[b * 128 + k] * lw1[k * 256 + j];
        z1[o] = fmaxf(s, 0.f);
    }
    __syncthreads();
    for (int o = tid; o < 4 * 64; o += 256) {
        int b = o >> 6, j = o & 63;
        float s = lb2[j];
        for (int k = 0; k < 256; ++k) s += z1[b * 256 + k] * lw2[k * 64 + j];
        z2[o] = fmaxf(s, 0.f);
    }
    __syncthreads();
    if (tid < 64) {
        int b = tid >> 4, j = tid & 15;
        float s = lb3[j];
        for (int k = 0; k < 64; ++k) s += z2[b * 64 + k] * lw3[k * 16 + j];
        z3[tid] = fmaxf(s, 0.f);
    }
    __syncthreads();
    if (tid < 4) {
        float s = lb4[0];
        for (int k = 0; k < 16; ++k) s += z3[tid * 16 + k] * lw4[k];
        out[tid] = s;
    }
}

// ---------------- launcher ----------------

extern "C" void kernel_launch(void* const* d_in, const int* in_sizes, int n_in,
                              void* d_out, int out_size, void* d_ws, size_t ws_size,
                              hipStream_t stream) {
    const float* x    = (const float*)d_in[0];
    const int*   ei   = (const int*)d_in[1];
    const int*   pmask = (const int*)d_in[2];
    const float* W1 = (const float*)d_in[3];  const float* b1 = (const float*)d_in[4];
    const float* W2 = (const float*)d_in[5];  const float* b2 = (const float*)d_in[6];
    const float* W3 = (const float*)d_in[7];  const float* b3 = (const float*)d_in[8];
    const float* lw1 = (const float*)d_in[9];  const float* lb1 = (const float*)d_in[10];
    const float* lw2 = (const float*)d_in[11]; const float* lb2 = (const float*)d_in[12];
    const float* lw3 = (const float*)d_in[13]; const float* lb3 = (const float*)d_in[14];
    const float* lw4 = (const float*)d_in[15]; const float* lb4 = (const float*)d_in[16];
    float* out = (float*)d_out;

    const int E = in_sizes[1] / 2;
    const int NODES = in_sizes[0] / F_IN;
    const int NB = 4;
    const int NPER = NODES / NB;   // 17000
    const int NBUK = (NODES + 255) >> 8;
    const int NSB = (NODES + SCAN_TILE) / SCAN_TILE;   // scan blocks covering [0, NODES]
    const int* esrc = ei;
    const int* edst = ei + E;

    char* w = (char*)d_ws;
    size_t off = 0;
    auto alloc = [&](size_t bytes) -> void* {
        void* p = w + off;
        off = align256(off + bytes);
        return p;
    };
    int*   degc = (int*)  alloc((size_t)NODES * 4);
    float* dinv = (float*)alloc((size_t)NODES * 4);
    int*   offs = (int*)  alloc((size_t)(NODES + 1) * 4);
    int*   gcur = (int*)  alloc((size_t)NBUK * 4);
    int*   bsum = (int*)  alloc((size_t)NSB * 4);
    int*   bpre = (int*)  alloc((size_t)NSB * 4);
    int2*  ebuf = (int2*) alloc((size_t)E * 8);
    int*   csr  = (int*)  alloc((size_t)(E + NODES) * 4);
    __hip_bfloat16* G   = (__hip_bfloat16*)alloc((size_t)NODES * C * 2);
    __hip_bfloat16* A1  = (__hip_bfloat16*)alloc((size_t)NODES * C * 2);
    __hip_bfloat16* A2  = (__hip_bfloat16*)alloc((size_t)NODES * C * 2);
    __hip_bfloat16* Wsw = (__hip_bfloat16*)alloc((size_t)F_IN * C * 2);
    float* pooled = (float*)alloc((size_t)4 * C * 4);
    (void)ws_size; (void)n_in; (void)out_size;

    hipMemsetAsync(degc,   0, (size_t)NODES * 4, stream);
    hipMemsetAsync(pooled, 0, (size_t)4 * C * 4, stream);

    deg_count_kernel<<<(E + 255) / 256, 256, 0, stream>>>(edst, degc, E);
    scan1_kernel<<<NSB, 256, 0, stream>>>(degc, bsum, NODES);
    scan2_kernel<<<1, 256, 0, stream>>>(bsum, bpre, NSB);
    scan3_kernel<<<NSB, 256, 0, stream>>>(degc, bpre, offs, dinv, gcur, NODES);
    partition_kernel<<<(E + CHUNK - 1) / CHUNK, 256, 0, stream>>>(esrc, edst, gcur, ebuf, E);
    csr_build_kernel<<<NBUK, 256, 0, stream>>>(ebuf, offs, csr, NODES);

    const int gblocks = (NODES + 127) / 128;
    dim3 pgrid((NPER + 127) / 128, NB);

    // layer 1 (K = 256, fp32 input fused-converted)
    wswz_kernel<<<(F_IN / 32 * 512 + 255) / 256, 256, 0, stream>>>(W1, Wsw, F_IN);
    mfma_gemm_kernel<true><<<gblocks, 256, F_IN * 256, stream>>>(x, Wsw, dinv, G, NODES, F_IN);
    agg_kernel<<<NODES, 64, 0, stream>>>(G, csr, offs, dinv, b1, A1);
    pool_kernel<<<pgrid, 64, 0, stream>>>(A1, pmask, pooled, NPER);
    // layer 2 (K = 128)
    wswz_kernel<<<(C / 32 * 512 + 255) / 256, 256, 0, stream>>>(W2, Wsw, C);
    mfma_gemm_kernel<false><<<gblocks, 256, C * 256, stream>>>(A1, Wsw, dinv, G, NODES, C);
    agg_kernel<<<NODES, 64, 0, stream>>>(G, csr, offs, dinv, b2, A2);
    pool_kernel<<<pgrid, 64, 0, stream>>>(A2, pmask, pooled, NPER);
    // layer 3 (K = 128)
    wswz_kernel<<<(C / 32 * 512 + 255) / 256, 256, 0, stream>>>(W3, Wsw, C);
    mfma_gemm_kernel<false><<<gblocks, 256, C * 256, stream>>>(A2, Wsw, dinv, G, NODES, C);
    agg_kernel<<<NODES, 64, 0, stream>>>(G, csr, offs, dinv, b3, A1);
    pool_kernel<<<pgrid, 64, 0, stream>>>(A1, pmask, pooled, NPER);

    mlp_kernel<<<1, 256, 0, stream>>>(pooled, lw1, lb1, lw2, lb2, lw3, lb3, lw4, lb4, out);
}